// Round 3
// baseline (7384.010 us; speedup 1.0000x reference)
//
#include <hip/hip_runtime.h>
#include <hip/hip_bf16.h>
#include <math.h>

#define TT 2048
#define EE 512
#define HH 512          // Hh
#define G4 2048         // 4*Hh
#define NTAGS 5
#define START_TAG 3
#define STOP_TAG 4
#define NEGV -10000.0f

// ---------------------------------------------------------------------------
// GEMM: G[t][n] = sum_k emb[sent[t]][k] * w[n][k] + bias[n]
// M=T=2048, N=4Hh=2048, K=E=512. 128x128 tile, 8x8/thread, BK=16.
// ---------------------------------------------------------------------------
#define BM 128
#define BN 128
#define BK 16

__global__ __launch_bounds__(256) void gemm_ih_kernel(
    const int* __restrict__ sent, const float* __restrict__ emb,
    const float* __restrict__ w, const float* __restrict__ bias,
    float* __restrict__ G)
{
    __shared__ float As[BK][BM + 4];
    __shared__ float Bs[BK][BN + 4];
    const int tid = threadIdx.x;
    const int t0 = blockIdx.y * BM;
    const int n0 = blockIdx.x * BN;
    const int lrow = tid >> 1;          // 0..127
    const int lk   = (tid & 1) * 8;     // 0 or 8
    const float* ap = emb + (long)sent[t0 + lrow] * EE + lk;
    const float* bp = w + (long)(n0 + lrow) * EE + lk;
    const int ty = tid >> 4, tx = tid & 15;

    float acc[8][8];
#pragma unroll
    for (int i = 0; i < 8; ++i)
#pragma unroll
        for (int j = 0; j < 8; ++j) acc[i][j] = 0.f;

    for (int k = 0; k < EE; k += BK) {
        float4 a0 = *(const float4*)(ap + k);
        float4 a1 = *(const float4*)(ap + k + 4);
        float4 b0 = *(const float4*)(bp + k);
        float4 b1 = *(const float4*)(bp + k + 4);
        __syncthreads();
        As[lk+0][lrow]=a0.x; As[lk+1][lrow]=a0.y; As[lk+2][lrow]=a0.z; As[lk+3][lrow]=a0.w;
        As[lk+4][lrow]=a1.x; As[lk+5][lrow]=a1.y; As[lk+6][lrow]=a1.z; As[lk+7][lrow]=a1.w;
        Bs[lk+0][lrow]=b0.x; Bs[lk+1][lrow]=b0.y; Bs[lk+2][lrow]=b0.z; Bs[lk+3][lrow]=b0.w;
        Bs[lk+4][lrow]=b1.x; Bs[lk+5][lrow]=b1.y; Bs[lk+6][lrow]=b1.z; Bs[lk+7][lrow]=b1.w;
        __syncthreads();
#pragma unroll
        for (int kk = 0; kk < BK; ++kk) {
            float a[8], b[8];
            *(float4*)&a[0] = *(const float4*)&As[kk][ty*8];
            *(float4*)&a[4] = *(const float4*)&As[kk][ty*8 + 4];
            *(float4*)&b[0] = *(const float4*)&Bs[kk][tx*8];
            *(float4*)&b[4] = *(const float4*)&Bs[kk][tx*8 + 4];
#pragma unroll
            for (int i = 0; i < 8; ++i)
#pragma unroll
                for (int j = 0; j < 8; ++j) acc[i][j] += a[i] * b[j];
        }
    }
    float bv[8];
#pragma unroll
    for (int j = 0; j < 8; ++j) bv[j] = bias[n0 + tx*8 + j];
#pragma unroll
    for (int i = 0; i < 8; ++i) {
        const long t = t0 + ty*8 + i;
        float4 o0 = make_float4(acc[i][0]+bv[0], acc[i][1]+bv[1], acc[i][2]+bv[2], acc[i][3]+bv[3]);
        float4 o1 = make_float4(acc[i][4]+bv[4], acc[i][5]+bv[5], acc[i][6]+bv[6], acc[i][7]+bv[7]);
        *(float4*)&G[t*G4 + n0 + tx*8]     = o0;
        *(float4*)&G[t*G4 + n0 + tx*8 + 4] = o1;
    }
}

// ---------------------------------------------------------------------------
// tagged-atom helpers: {hi32 = step tag, lo32 = float payload}
// ---------------------------------------------------------------------------
__device__ __forceinline__ unsigned long long pack_ht(unsigned int tag, float v) {
    return ((unsigned long long)tag << 32) | (unsigned long long)__float_as_uint(v);
}

// init: seed parity-0 slot with h0 (tag 0), parity-1 slot with invalid tag
__global__ void init_kernel(const float* __restrict__ h0,
                            unsigned long long* __restrict__ htag)
{
    for (int i = threadIdx.x; i < 2 * HH; i += 256) {
        const int dir = i >> 9, k = i & 511;
        htag[(dir * 2 + 0) * HH + k] = pack_ht(0u, h0[i]);
        htag[(dir * 2 + 1) * HH + k] = pack_ht(0xFFFFFFFFu, 0.f);
    }
}

// ---------------------------------------------------------------------------
// LSTM recurrence: 128 blocks (64/dir) x 256 thr. Weights pinned in VGPRs.
// Per block: 8 h-elements (rows), each row = 32 lanes x 16 k.
// Sync: tagged 64-bit agent-scope atomics; wave 0 polls (dedup), LDS bcast.
// ---------------------------------------------------------------------------
#define NB 64

__global__ __launch_bounds__(256, 1) void lstm_rec_kernel(
    const float* __restrict__ Gf, const float* __restrict__ Gb,
    const float* __restrict__ whh_f, const float* __restrict__ whh_b,
    const float* __restrict__ c0,
    unsigned long long* __restrict__ htag, float* __restrict__ hs)
{
    const int dir = blockIdx.x >> 6;
    const int blk = blockIdx.x & 63;
    const int tid = threadIdx.x;
    const int kg  = tid & 31;     // k-group: 16 k each
    const int e   = tid >> 5;     // element 0..7
    const int row = blk * 8 + e;  // h index this thread's rows belong to
    const float* whh = dir ? whh_b : whh_f;
    const float* Gd  = dir ? Gb : Gf;
    unsigned long long* hslots = htag + (long)dir * 2 * HH;  // [2][HH]

    // this thread's weight slice: 4 gates x 16 k = 64 floats, pinned in VGPRs
    float4 w[4][4];
#pragma unroll
    for (int g = 0; g < 4; ++g) {
        const float* wr = whh + (long)(g * HH + row) * HH + kg * 16;
#pragma unroll
        for (int v = 0; v < 4; ++v) w[g][v] = *(const float4*)(wr + v * 4);
    }
#pragma unroll
    for (int g = 0; g < 4; ++g)
#pragma unroll
        for (int v = 0; v < 4; ++v)
            asm volatile("" : "+v"(w[g][v].x), "+v"(w[g][v].y),
                              "+v"(w[g][v].z), "+v"(w[g][v].w));

    float c = c0[dir * HH + row];

    __shared__ float hl[2][HH + 64];   // parity double-buffer, +4 pad per 32

    float gc[4] = {0.f,0.f,0.f,0.f}, gn[4];
    if (kg == 0) {
        const int trow = dir ? (TT - 1) : 0;
#pragma unroll
        for (int g = 0; g < 4; ++g) gc[g] = Gd[(long)trow * G4 + g * HH + row];
    }

    const int pbase = tid * 8;                   // poller: 8 atoms (64B)
    const int pb = kg * 16 + ((kg >> 1) << 2);   // padded LDS read base

    for (int t = 0; t < TT; ++t) {
        const int p = t & 1;
        const unsigned int tagv = (unsigned int)t;
        unsigned long long* slot = hslots + p * HH;

        // wave 0 polls all 512 atoms (8 per lane, independent loads per retry)
        if (tid < 64) {
            unsigned long long a[8];
            for (;;) {
#pragma unroll
                for (int j = 0; j < 8; ++j)
                    a[j] = __hip_atomic_load(&slot[pbase + j], __ATOMIC_RELAXED,
                                             __HIP_MEMORY_SCOPE_AGENT);
                bool ok = true;
#pragma unroll
                for (int j = 0; j < 8; ++j) ok &= ((unsigned int)(a[j] >> 32) == tagv);
                if (ok) break;
            }
#pragma unroll
            for (int j = 0; j < 8; ++j) {
                const int idx = pbase + j;
                hl[p][idx + ((idx >> 5) << 2)] = __uint_as_float((unsigned int)a[j]);
            }
        }

        // prefetch next step's G rows (hidden under poll + barrier)
        if (kg == 0) {
            const int tn = (t + 1 < TT) ? (t + 1) : t;
            const int trow = dir ? (TT - 1 - tn) : tn;
#pragma unroll
            for (int g = 0; g < 4; ++g) gn[g] = Gd[(long)trow * G4 + g * HH + row];
        }
        __syncthreads();   // h staged; also orders prior slot reads vs publishes

        float4 h4[4];
#pragma unroll
        for (int i = 0; i < 4; ++i) h4[i] = *(const float4*)&hl[p][pb + i * 4];

        float acc[4];
#pragma unroll
        for (int g = 0; g < 4; ++g) {
            float s = 0.f;
#pragma unroll
            for (int v = 0; v < 4; ++v)
                s += w[g][v].x*h4[v].x + w[g][v].y*h4[v].y + w[g][v].z*h4[v].z + w[g][v].w*h4[v].w;
            acc[g] = s;
        }
#pragma unroll
        for (int m = 1; m < 32; m <<= 1) {
#pragma unroll
            for (int g = 0; g < 4; ++g) acc[g] += __shfl_xor(acc[g], m);
        }

        if (kg == 0) {
            const float xi = acc[0] + gc[0];
            const float xf = acc[1] + gc[1];
            const float xg = acc[2] + gc[2];
            const float xo = acc[3] + gc[3];
            const float si = 1.f / (1.f + __expf(-xi));
            const float sf = 1.f / (1.f + __expf(-xf));
            const float sg = tanhf(xg);
            const float so = 1.f / (1.f + __expf(-xo));
            c = sf * c + si * sg;
            const float h = so * tanhf(c);
            const int trow = dir ? (TT - 1 - t) : t;
            hs[((long)dir * TT + trow) * HH + row] = h;
            // publish {tag t+1, h} in one agent-scope atom — no fence needed
            __hip_atomic_store(&hslots[((t + 1) & 1) * HH + row],
                               pack_ht((unsigned int)(t + 1), h),
                               __ATOMIC_RELAXED, __HIP_MEMORY_SCOPE_AGENT);
            gc[0]=gn[0]; gc[1]=gn[1]; gc[2]=gn[2]; gc[3]=gn[3];
        }
    }
}

// ---------------------------------------------------------------------------
// feats[t][j] = b_out[j] + hf[t]·w_out[j][0:512] + hb[t]·w_out[j][512:1024]
// ---------------------------------------------------------------------------
__global__ __launch_bounds__(64) void feats_kernel(
    const float* __restrict__ hs, const float* __restrict__ w_out,
    const float* __restrict__ b_out, float* __restrict__ feats)
{
    const int t = blockIdx.x;
    const int lane = threadIdx.x;
    const float* src = (lane < 32) ? (hs + (long)t * HH + lane * 16)
                                   : (hs + (long)(TT + t) * HH + (lane - 32) * 16);
    float x[16];
#pragma unroll
    for (int i = 0; i < 4; ++i) *(float4*)&x[i*4] = *(const float4*)(src + i*4);
    const int kglob = lane * 16;
    float pj[NTAGS];
#pragma unroll
    for (int j = 0; j < NTAGS; ++j) {
        const float* wr = w_out + (long)j * 1024 + kglob;
        float s = 0.f;
#pragma unroll
        for (int i = 0; i < 4; ++i) {
            float4 wv = *(const float4*)(wr + i*4);
            s += wv.x*x[i*4] + wv.y*x[i*4+1] + wv.z*x[i*4+2] + wv.w*x[i*4+3];
        }
        pj[j] = s;
    }
#pragma unroll
    for (int m = 1; m < 64; m <<= 1) {
#pragma unroll
        for (int j = 0; j < NTAGS; ++j) pj[j] += __shfl_xor(pj[j], m);
    }
    if (lane == 0) {
#pragma unroll
        for (int j = 0; j < NTAGS; ++j) feats[(long)t * NTAGS + j] = pj[j] + b_out[j];
    }
}

// ---------------------------------------------------------------------------
// CRF forward scan -> scalar log-partition
// ---------------------------------------------------------------------------
__global__ __launch_bounds__(64) void crf_kernel(
    const float* __restrict__ feats, const float* __restrict__ trans,
    float* __restrict__ out)
{
    __shared__ float fl[TT * NTAGS];   // 40 KB
    const int lane = threadIdx.x;
    for (int i = lane; i < TT * NTAGS; i += 64) fl[i] = feats[i];
    __syncthreads();

    const int j = (lane < NTAGS) ? lane : 0;
    float tr[NTAGS];
#pragma unroll
    for (int i = 0; i < NTAGS; ++i) tr[i] = trans[j * NTAGS + i];
    float fv = (j == START_TAG) ? 0.f : NEGV;

    for (int t = 0; t < TT; ++t) {
        const float x0 = __shfl(fv, 0) + tr[0];
        const float x1 = __shfl(fv, 1) + tr[1];
        const float x2 = __shfl(fv, 2) + tr[2];
        const float x3 = __shfl(fv, 3) + tr[3];
        const float x4 = __shfl(fv, 4) + tr[4];
        const float m = fmaxf(fmaxf(fmaxf(x0, x1), fmaxf(x2, x3)), x4);
        const float s = expf(x0-m) + expf(x1-m) + expf(x2-m) + expf(x3-m) + expf(x4-m);
        fv = fl[t * NTAGS + j] + m + logf(s);
    }
    const float xx = fv + trans[STOP_TAG * NTAGS + j];
    const float y0 = __shfl(xx, 0), y1 = __shfl(xx, 1), y2 = __shfl(xx, 2),
                y3 = __shfl(xx, 3), y4 = __shfl(xx, 4);
    if (lane == 0) {
        const float m = fmaxf(fmaxf(fmaxf(y0, y1), fmaxf(y2, y3)), y4);
        const float s = expf(y0-m) + expf(y1-m) + expf(y2-m) + expf(y3-m) + expf(y4-m);
        out[0] = m + logf(s);
    }
}

// ---------------------------------------------------------------------------
extern "C" void kernel_launch(void* const* d_in, const int* in_sizes, int n_in,
                              void* d_out, int out_size, void* d_ws, size_t ws_size,
                              hipStream_t stream)
{
    (void)in_sizes; (void)n_in; (void)out_size; (void)ws_size;
    const int*   sent  = (const int*)d_in[0];
    const float* emb   = (const float*)d_in[1];
    const float* wihf  = (const float*)d_in[2];
    const float* whhf  = (const float*)d_in[3];
    const float* bf    = (const float*)d_in[4];
    const float* wihb  = (const float*)d_in[5];
    const float* whhb  = (const float*)d_in[6];
    const float* bb    = (const float*)d_in[7];
    const float* wout  = (const float*)d_in[8];
    const float* bout  = (const float*)d_in[9];
    const float* trans = (const float*)d_in[10];
    const float* h0    = (const float*)d_in[11];
    const float* c0    = (const float*)d_in[12];
    float* out = (float*)d_out;

    char* ws = (char*)d_ws;
    float* Gf    = (float*)(ws);                       // 16 MB
    float* Gb    = (float*)(ws + 16777216);            // 16 MB
    float* hs    = (float*)(ws + 33554432);            // 8 MB   [2][T][Hh]
    float* feats = (float*)(ws + 41943040);            // 40 KB
    unsigned long long* htag = (unsigned long long*)(ws + 42000384); // 16 KB [2][2][HH]

    init_kernel<<<1, 256, 0, stream>>>(h0, htag);
    gemm_ih_kernel<<<dim3(G4 / BN, TT / BM), 256, 0, stream>>>(sent, emb, wihf, bf, Gf);
    gemm_ih_kernel<<<dim3(G4 / BN, TT / BM), 256, 0, stream>>>(sent, emb, wihb, bb, Gb);
    lstm_rec_kernel<<<2 * NB, 256, 0, stream>>>(Gf, Gb, whhf, whhb, c0, htag, hs);
    feats_kernel<<<TT, 64, 0, stream>>>(hs, wout, bout, feats);
    crf_kernel<<<1, 64, 0, stream>>>(feats, trans, out);
}

// Round 4
// 5237.316 us; speedup vs baseline: 1.4099x; 1.4099x over previous
//
#include <hip/hip_runtime.h>
#include <hip/hip_bf16.h>
#include <math.h>

#define TT 2048
#define EE 512
#define HH 512          // Hh
#define G4 2048         // 4*Hh
#define NTAGS 5
#define START_TAG 3
#define STOP_TAG 4
#define NEGV -10000.0f

// ---------------------------------------------------------------------------
// GEMM: G[t][n] = sum_k emb[sent[t]][k] * w[n][k] + bias[n]
// M=T=2048, N=4Hh=2048, K=E=512. 128x128 tile, 8x8/thread, BK=16.
// ---------------------------------------------------------------------------
#define BM 128
#define BN 128
#define BK 16

__global__ __launch_bounds__(256) void gemm_ih_kernel(
    const int* __restrict__ sent, const float* __restrict__ emb,
    const float* __restrict__ w, const float* __restrict__ bias,
    float* __restrict__ G)
{
    __shared__ float As[BK][BM + 4];
    __shared__ float Bs[BK][BN + 4];
    const int tid = threadIdx.x;
    const int t0 = blockIdx.y * BM;
    const int n0 = blockIdx.x * BN;
    const int lrow = tid >> 1;          // 0..127
    const int lk   = (tid & 1) * 8;     // 0 or 8
    const float* ap = emb + (long)sent[t0 + lrow] * EE + lk;
    const float* bp = w + (long)(n0 + lrow) * EE + lk;
    const int ty = tid >> 4, tx = tid & 15;

    float acc[8][8];
#pragma unroll
    for (int i = 0; i < 8; ++i)
#pragma unroll
        for (int j = 0; j < 8; ++j) acc[i][j] = 0.f;

    for (int k = 0; k < EE; k += BK) {
        float4 a0 = *(const float4*)(ap + k);
        float4 a1 = *(const float4*)(ap + k + 4);
        float4 b0 = *(const float4*)(bp + k);
        float4 b1 = *(const float4*)(bp + k + 4);
        __syncthreads();
        As[lk+0][lrow]=a0.x; As[lk+1][lrow]=a0.y; As[lk+2][lrow]=a0.z; As[lk+3][lrow]=a0.w;
        As[lk+4][lrow]=a1.x; As[lk+5][lrow]=a1.y; As[lk+6][lrow]=a1.z; As[lk+7][lrow]=a1.w;
        Bs[lk+0][lrow]=b0.x; Bs[lk+1][lrow]=b0.y; Bs[lk+2][lrow]=b0.z; Bs[lk+3][lrow]=b0.w;
        Bs[lk+4][lrow]=b1.x; Bs[lk+5][lrow]=b1.y; Bs[lk+6][lrow]=b1.z; Bs[lk+7][lrow]=b1.w;
        __syncthreads();
#pragma unroll
        for (int kk = 0; kk < BK; ++kk) {
            float a[8], b[8];
            *(float4*)&a[0] = *(const float4*)&As[kk][ty*8];
            *(float4*)&a[4] = *(const float4*)&As[kk][ty*8 + 4];
            *(float4*)&b[0] = *(const float4*)&Bs[kk][tx*8];
            *(float4*)&b[4] = *(const float4*)&Bs[kk][tx*8 + 4];
#pragma unroll
            for (int i = 0; i < 8; ++i)
#pragma unroll
                for (int j = 0; j < 8; ++j) acc[i][j] += a[i] * b[j];
        }
    }
    float bv[8];
#pragma unroll
    for (int j = 0; j < 8; ++j) bv[j] = bias[n0 + tx*8 + j];
#pragma unroll
    for (int i = 0; i < 8; ++i) {
        const long t = t0 + ty*8 + i;
        float4 o0 = make_float4(acc[i][0]+bv[0], acc[i][1]+bv[1], acc[i][2]+bv[2], acc[i][3]+bv[3]);
        float4 o1 = make_float4(acc[i][4]+bv[4], acc[i][5]+bv[5], acc[i][6]+bv[6], acc[i][7]+bv[7]);
        *(float4*)&G[t*G4 + n0 + tx*8]     = o0;
        *(float4*)&G[t*G4 + n0 + tx*8 + 4] = o1;
    }
}

// ---------------------------------------------------------------------------
// tagged-atom helpers: {hi32 = step tag, lo32 = float payload}
// ---------------------------------------------------------------------------
__device__ __forceinline__ unsigned long long pack_ht(unsigned int tag, float v) {
    return ((unsigned long long)tag << 32) | (unsigned long long)__float_as_uint(v);
}

// init: seed parity-0 slot with h0 (tag 0), parity-1 slot with invalid tag
__global__ void init_kernel(const float* __restrict__ h0,
                            unsigned long long* __restrict__ htag)
{
    for (int i = threadIdx.x; i < 2 * HH; i += 256) {
        const int dir = i >> 9, k = i & 511;
        htag[(dir * 2 + 0) * HH + k] = pack_ht(0u, h0[i]);
        htag[(dir * 2 + 1) * HH + k] = pack_ht(0xFFFFFFFFu, 0.f);
    }
}

// fast stable tanh via __expf
__device__ __forceinline__ float fast_tanh(float x) {
    const float ax = fabsf(x);
    const float z = __expf(-2.f * ax);
    const float t = (1.f - z) / (1.f + z);
    return copysignf(t, x);
}

// ---------------------------------------------------------------------------
// LSTM recurrence: 64 blocks (32/dir) x 256 thr. Weights in VGPR/AGPR.
// Per block: 16 h-elements (rows), each row = 16 lanes x 32 k.
// Sync: tagged 64-bit agent-scope atomics, per-thread poll + s_sleep backoff.
// ---------------------------------------------------------------------------
#define NB 32

__global__ __launch_bounds__(256, 1) void lstm_rec_kernel(
    const float* __restrict__ Gf, const float* __restrict__ Gb,
    const float* __restrict__ whh_f, const float* __restrict__ whh_b,
    const float* __restrict__ c0,
    unsigned long long* __restrict__ htag, float* __restrict__ hs)
{
    const int dir = blockIdx.x >> 5;
    const int blk = blockIdx.x & 31;
    const int tid = threadIdx.x;
    const int kg  = tid & 15;     // k-group: 32 k each
    const int e   = tid >> 4;     // element 0..15
    const int row = blk * 16 + e; // h index this thread's rows belong to
    const float* whh = dir ? whh_b : whh_f;
    const float* Gd  = dir ? Gb : Gf;
    unsigned long long* hslots = htag + (long)dir * 2 * HH;  // [2][HH]

    // this thread's weight slice: 4 gates x 32 k = 128 floats (VGPR/AGPR)
    float4 w[4][8];
#pragma unroll
    for (int g = 0; g < 4; ++g) {
        const float* wr = whh + (long)(g * HH + row) * HH + kg * 32;
#pragma unroll
        for (int v = 0; v < 8; ++v) w[g][v] = *(const float4*)(wr + v * 4);
    }
#pragma unroll
    for (int g = 0; g < 4; ++g)
#pragma unroll
        for (int v = 0; v < 8; ++v)
            asm volatile("" : "+v"(w[g][v].x), "+v"(w[g][v].y),
                              "+v"(w[g][v].z), "+v"(w[g][v].w));

    float c = c0[dir * HH + row];

    __shared__ float hl[2][HH + 64];   // parity double-buffer, +4 pad per 32

    float gc[4] = {0.f,0.f,0.f,0.f}, gn[4];
    if (kg == 0) {
        const int trow = dir ? (TT - 1) : 0;
#pragma unroll
        for (int g = 0; g < 4; ++g) gc[g] = Gd[(long)trow * G4 + g * HH + row];
    }

    const int i0 = tid * 2;                      // two atoms this thread polls
    const int pi = i0 + ((i0 >> 5) << 2);        // padded LDS store index
    const int pb = kg * 36;                      // padded LDS read base (32->36)

    for (int t = 0; t < TT; ++t) {
        const int p = t & 1;
        const unsigned int tagv = (unsigned int)t;
        unsigned long long* slot = hslots + p * HH;

        // prefetch next step's G rows first (independent vmem, hidden by poll)
        if (kg == 0) {
            const int tn = (t + 1 < TT) ? (t + 1) : t;
            const int trow = dir ? (TT - 1 - tn) : tn;
#pragma unroll
            for (int g = 0; g < 4; ++g) gn[g] = Gd[(long)trow * G4 + g * HH + row];
        }

        // per-thread poll of 2 tagged atoms with wave-coalesced backoff
        unsigned long long a0 = __hip_atomic_load(&slot[i0],   __ATOMIC_RELAXED, __HIP_MEMORY_SCOPE_AGENT);
        unsigned long long a1 = __hip_atomic_load(&slot[i0+1], __ATOMIC_RELAXED, __HIP_MEMORY_SCOPE_AGENT);
        while (((unsigned int)(a0 >> 32) != tagv) | ((unsigned int)(a1 >> 32) != tagv)) {
            __builtin_amdgcn_s_sleep(1);   // ~64 cy; calms L3 line contention
            a0 = __hip_atomic_load(&slot[i0],   __ATOMIC_RELAXED, __HIP_MEMORY_SCOPE_AGENT);
            a1 = __hip_atomic_load(&slot[i0+1], __ATOMIC_RELAXED, __HIP_MEMORY_SCOPE_AGENT);
        }
        hl[p][pi]     = __uint_as_float((unsigned int)a0);
        hl[p][pi + 1] = __uint_as_float((unsigned int)a1);

        __syncthreads();   // h staged; also orders prior slot reads vs publishes

        float4 h4[8];
#pragma unroll
        for (int i = 0; i < 8; ++i) h4[i] = *(const float4*)&hl[p][pb + i * 4];

        float acc[4];
#pragma unroll
        for (int g = 0; g < 4; ++g) {
            float s = 0.f;
#pragma unroll
            for (int v = 0; v < 8; ++v)
                s += w[g][v].x*h4[v].x + w[g][v].y*h4[v].y + w[g][v].z*h4[v].z + w[g][v].w*h4[v].w;
            acc[g] = s;
        }
#pragma unroll
        for (int m = 1; m < 16; m <<= 1) {
#pragma unroll
            for (int g = 0; g < 4; ++g) acc[g] += __shfl_xor(acc[g], m);
        }

        if (kg == 0) {
            const float xi = acc[0] + gc[0];
            const float xf = acc[1] + gc[1];
            const float xg = acc[2] + gc[2];
            const float xo = acc[3] + gc[3];
            const float si = 1.f / (1.f + __expf(-xi));
            const float sf = 1.f / (1.f + __expf(-xf));
            const float sg = fast_tanh(xg);
            const float so = 1.f / (1.f + __expf(-xo));
            c = sf * c + si * sg;
            const float h = so * fast_tanh(c);
            const int trow = dir ? (TT - 1 - t) : t;
            hs[((long)dir * TT + trow) * HH + row] = h;
            // publish {tag t+1, h} in one agent-scope atom — no fence needed
            __hip_atomic_store(&hslots[((t + 1) & 1) * HH + row],
                               pack_ht((unsigned int)(t + 1), h),
                               __ATOMIC_RELAXED, __HIP_MEMORY_SCOPE_AGENT);
            gc[0]=gn[0]; gc[1]=gn[1]; gc[2]=gn[2]; gc[3]=gn[3];
        }
    }
}

// ---------------------------------------------------------------------------
// feats[t][j] = b_out[j] + hf[t]·w_out[j][0:512] + hb[t]·w_out[j][512:1024]
// ---------------------------------------------------------------------------
__global__ __launch_bounds__(64) void feats_kernel(
    const float* __restrict__ hs, const float* __restrict__ w_out,
    const float* __restrict__ b_out, float* __restrict__ feats)
{
    const int t = blockIdx.x;
    const int lane = threadIdx.x;
    const float* src = (lane < 32) ? (hs + (long)t * HH + lane * 16)
                                   : (hs + (long)(TT + t) * HH + (lane - 32) * 16);
    float x[16];
#pragma unroll
    for (int i = 0; i < 4; ++i) *(float4*)&x[i*4] = *(const float4*)(src + i*4);
    const int kglob = lane * 16;
    float pj[NTAGS];
#pragma unroll
    for (int j = 0; j < NTAGS; ++j) {
        const float* wr = w_out + (long)j * 1024 + kglob;
        float s = 0.f;
#pragma unroll
        for (int i = 0; i < 4; ++i) {
            float4 wv = *(const float4*)(wr + i*4);
            s += wv.x*x[i*4] + wv.y*x[i*4+1] + wv.z*x[i*4+2] + wv.w*x[i*4+3];
        }
        pj[j] = s;
    }
#pragma unroll
    for (int m = 1; m < 64; m <<= 1) {
#pragma unroll
        for (int j = 0; j < NTAGS; ++j) pj[j] += __shfl_xor(pj[j], m);
    }
    if (lane == 0) {
#pragma unroll
        for (int j = 0; j < NTAGS; ++j) feats[(long)t * NTAGS + j] = pj[j] + b_out[j];
    }
}

// ---------------------------------------------------------------------------
// CRF forward scan -> scalar log-partition
// ---------------------------------------------------------------------------
__global__ __launch_bounds__(64) void crf_kernel(
    const float* __restrict__ feats, const float* __restrict__ trans,
    float* __restrict__ out)
{
    __shared__ float fl[TT * NTAGS];   // 40 KB
    const int lane = threadIdx.x;
    for (int i = lane; i < TT * NTAGS; i += 64) fl[i] = feats[i];
    __syncthreads();

    const int j = (lane < NTAGS) ? lane : 0;
    float tr[NTAGS];
#pragma unroll
    for (int i = 0; i < NTAGS; ++i) tr[i] = trans[j * NTAGS + i];
    float fv = (j == START_TAG) ? 0.f : NEGV;

    for (int t = 0; t < TT; ++t) {
        const float x0 = __shfl(fv, 0) + tr[0];
        const float x1 = __shfl(fv, 1) + tr[1];
        const float x2 = __shfl(fv, 2) + tr[2];
        const float x3 = __shfl(fv, 3) + tr[3];
        const float x4 = __shfl(fv, 4) + tr[4];
        const float m = fmaxf(fmaxf(fmaxf(x0, x1), fmaxf(x2, x3)), x4);
        const float s = expf(x0-m) + expf(x1-m) + expf(x2-m) + expf(x3-m) + expf(x4-m);
        fv = fl[t * NTAGS + j] + m + logf(s);
    }
    const float xx = fv + trans[STOP_TAG * NTAGS + j];
    const float y0 = __shfl(xx, 0), y1 = __shfl(xx, 1), y2 = __shfl(xx, 2),
                y3 = __shfl(xx, 3), y4 = __shfl(xx, 4);
    if (lane == 0) {
        const float m = fmaxf(fmaxf(fmaxf(y0, y1), fmaxf(y2, y3)), y4);
        const float s = expf(y0-m) + expf(y1-m) + expf(y2-m) + expf(y3-m) + expf(y4-m);
        out[0] = m + logf(s);
    }
}

// ---------------------------------------------------------------------------
extern "C" void kernel_launch(void* const* d_in, const int* in_sizes, int n_in,
                              void* d_out, int out_size, void* d_ws, size_t ws_size,
                              hipStream_t stream)
{
    (void)in_sizes; (void)n_in; (void)out_size; (void)ws_size;
    const int*   sent  = (const int*)d_in[0];
    const float* emb   = (const float*)d_in[1];
    const float* wihf  = (const float*)d_in[2];
    const float* whhf  = (const float*)d_in[3];
    const float* bf    = (const float*)d_in[4];
    const float* wihb  = (const float*)d_in[5];
    const float* whhb  = (const float*)d_in[6];
    const float* bb    = (const float*)d_in[7];
    const float* wout  = (const float*)d_in[8];
    const float* bout  = (const float*)d_in[9];
    const float* trans = (const float*)d_in[10];
    const float* h0    = (const float*)d_in[11];
    const float* c0    = (const float*)d_in[12];
    float* out = (float*)d_out;

    char* ws = (char*)d_ws;
    float* Gf    = (float*)(ws);                       // 16 MB
    float* Gb    = (float*)(ws + 16777216);            // 16 MB
    float* hs    = (float*)(ws + 33554432);            // 8 MB   [2][T][Hh]
    float* feats = (float*)(ws + 41943040);            // 40 KB
    unsigned long long* htag = (unsigned long long*)(ws + 42000384); // 16 KB [2][2][HH]

    init_kernel<<<1, 256, 0, stream>>>(h0, htag);
    gemm_ih_kernel<<<dim3(G4 / BN, TT / BM), 256, 0, stream>>>(sent, emb, wihf, bf, Gf);
    gemm_ih_kernel<<<dim3(G4 / BN, TT / BM), 256, 0, stream>>>(sent, emb, wihb, bb, Gb);
    lstm_rec_kernel<<<2 * NB, 256, 0, stream>>>(Gf, Gb, whhf, whhb, c0, htag, hs);
    feats_kernel<<<TT, 64, 0, stream>>>(hs, wout, bout, feats);
    crf_kernel<<<1, 64, 0, stream>>>(feats, trans, out);
}